// Round 1
// baseline (585.356 us; speedup 1.0000x reference)
//
#include <hip/hip_runtime.h>
#include <hip/hip_bf16.h>

#define N_NODES 50000
#define SEQ 12
#define CH 128
#define BS 4
#define TILE 64
#define PAD_ROW 132   // floats per LDS row (pad 128 -> 132 to break bank-conflict stride)
#define NTILES ((N_NODES + TILE - 1) / TILE)   // 782
#define NUNITS (NTILES * BS)                   // 3128

typedef short bf16x8 __attribute__((ext_vector_type(8)));
typedef float f32x4 __attribute__((ext_vector_type(4)));

__device__ __forceinline__ float bflo(unsigned int u) { return __uint_as_float(u << 16); }
__device__ __forceinline__ float bfhi(unsigned int u) { return __uint_as_float(u & 0xFFFF0000u); }

// ---- hand-rolled grid barrier (sense-reversal, self-resetting across graph replays) ----
__device__ unsigned int g_bar_count;
__device__ unsigned int g_bar_gen;

__device__ __forceinline__ void grid_barrier(int nblk) {
    __syncthreads();   // all block stores drained (compiler emits vmcnt(0) before s_barrier)
    if (threadIdx.x == 0) {
        __threadfence();   // agent-scope release: write back this XCD's L2
        unsigned int gen = __hip_atomic_load(&g_bar_gen, __ATOMIC_RELAXED, __HIP_MEMORY_SCOPE_AGENT);
        unsigned int pos = __hip_atomic_fetch_add(&g_bar_count, 1u, __ATOMIC_ACQ_REL, __HIP_MEMORY_SCOPE_AGENT);
        if (pos == (unsigned int)(nblk - 1)) {
            __hip_atomic_store(&g_bar_count, 0u, __ATOMIC_RELAXED, __HIP_MEMORY_SCOPE_AGENT);
            __hip_atomic_fetch_add(&g_bar_gen, 1u, __ATOMIC_RELEASE, __HIP_MEMORY_SCOPE_AGENT);
        } else {
            int guard = 0;
            while (__hip_atomic_load(&g_bar_gen, __ATOMIC_ACQUIRE, __HIP_MEMORY_SCOPE_AGENT) == gen) {
                __builtin_amdgcn_s_sleep(2);
                if (++guard > (1 << 22)) break;   // fail loud (wrong result), never hang
            }
        }
    }
    __syncthreads();
    __threadfence();   // agent-scope acquire: invalidate L1/L2 before reading peers' writes
}

// ---------------- Fused kernel: convert + barrier + gather + MFMA gate + store ----------------
__global__ __launch_bounds__(256, 4) void fused_gated_spiral(
    const float* __restrict__ x,
    const int* __restrict__ indices,
    const float* __restrict__ weight,
    const float* __restrict__ gate_w,
    const float* __restrict__ gate_b,
    unsigned short* __restrict__ xb,    // bf16 x workspace [BS*N_NODES*CH]
    unsigned short* __restrict__ gwb,   // bf16 gate_w [CH*CH]
    float* __restrict__ out,
    int nblk)
{
    __shared__ float spiral[TILE * PAD_ROW];   // 33792 B
    __shared__ int   idx_s[TILE * SEQ];        // 3072 B
    __shared__ float w_s[TILE * SEQ];          // 3072 B  (total 39936 <= 40960 for 4 blocks/CU)

    const int tid = threadIdx.x;

    // ---- Phase 0: fp32 -> bf16 conversion, grid-strided over the whole x ----
    {
        const size_t n8 = (size_t)BS * N_NODES * CH / 8;   // 3,200,000
        const size_t stride = (size_t)nblk * 256;
        for (size_t i = (size_t)blockIdx.x * 256 + tid; i < n8; i += stride) {
            float4 lo = *(const float4*)(x + i * 8);
            float4 hi = *(const float4*)(x + i * 8 + 4);
            union { bf16x8 v; __hip_bfloat16 h[8]; } o;
            o.h[0] = __float2bfloat16(lo.x); o.h[1] = __float2bfloat16(lo.y);
            o.h[2] = __float2bfloat16(lo.z); o.h[3] = __float2bfloat16(lo.w);
            o.h[4] = __float2bfloat16(hi.x); o.h[5] = __float2bfloat16(hi.y);
            o.h[6] = __float2bfloat16(hi.z); o.h[7] = __float2bfloat16(hi.w);
            *(bf16x8*)(xb + i * 8) = o.v;
        }
        const size_t g0 = (size_t)blockIdx.x * 256 + tid;
        if (g0 < (size_t)CH * CH / 8) {
            float4 lo = *(const float4*)(gate_w + g0 * 8);
            float4 hi = *(const float4*)(gate_w + g0 * 8 + 4);
            union { bf16x8 v; __hip_bfloat16 h[8]; } o;
            o.h[0] = __float2bfloat16(lo.x); o.h[1] = __float2bfloat16(lo.y);
            o.h[2] = __float2bfloat16(lo.z); o.h[3] = __float2bfloat16(lo.w);
            o.h[4] = __float2bfloat16(hi.x); o.h[5] = __float2bfloat16(hi.y);
            o.h[6] = __float2bfloat16(hi.z); o.h[7] = __float2bfloat16(hi.w);
            *(bf16x8*)(gwb + g0 * 8) = o.v;
        }
    }
    grid_barrier(nblk);

    // ---- Unit loop: (tile, batch) pairs grid-strided ----
    for (int unit = blockIdx.x; unit < NUNITS; unit += nblk) {
        const int tile = unit >> 2;
        const int b = unit & 3;
        const int node0 = tile * TILE;
        const unsigned short* xbb = xb + (size_t)b * N_NODES * CH;

        // -- Stage indices + weights for the tile into LDS (once, coalesced) --
        for (int k = tid; k < TILE * SEQ; k += 256) {
            int node = node0 + k / SEQ;
            if (node >= N_NODES) node = N_NODES - 1;
            int t = indices[(size_t)node * SEQ + (k % SEQ)];
            t = t < 0 ? 0 : (t >= N_NODES ? N_NODES - 1 : t);
            idx_s[k] = t;
            w_s[k] = weight[(size_t)node * SEQ + (k % SEQ)];
        }
        __syncthreads();

        // -- Phase 1: gather + weighted reduce. 16 threads/node, 8 ch each, 4 row-groups --
        {
            const int c0 = (tid & 15) * 8;     // channel offset (bf16 elements)
            const int rbase = tid >> 4;        // 0..15
            #pragma unroll 2
            for (int g = 0; g < 4; ++g) {
                const int r = g * 16 + rbase;
                int us[SEQ]; float wv[SEQ];
                #pragma unroll
                for (int s = 0; s < SEQ; ++s) {
                    us[s] = idx_s[r * SEQ + s];
                    wv[s] = w_s[r * SEQ + s];
                }
                float acc[8];
                #pragma unroll
                for (int i = 0; i < 8; ++i) acc[i] = 0.f;
                #pragma unroll
                for (int s = 0; s < SEQ; ++s) {
                    // 16 lanes of a node read its full 256B row contiguously
                    const uint4 d = *(const uint4*)(xbb + (size_t)us[s] * CH + c0);
                    const float ws = wv[s];
                    acc[0] += ws * bflo(d.x); acc[1] += ws * bfhi(d.x);
                    acc[2] += ws * bflo(d.y); acc[3] += ws * bfhi(d.y);
                    acc[4] += ws * bflo(d.z); acc[5] += ws * bfhi(d.z);
                    acc[6] += ws * bflo(d.w); acc[7] += ws * bfhi(d.w);
                }
                float* dst = spiral + r * PAD_ROW + c0;
                *(float4*)(dst)     = make_float4(acc[0], acc[1], acc[2], acc[3]);
                *(float4*)(dst + 4) = make_float4(acc[4], acc[5], acc[6], acc[7]);
            }
        }
        __syncthreads();

        // -- Phase 2: gate GEMM via MFMA 16x16x32_bf16 (proven layout) --
        {
            const int wave = tid >> 6;
            const int lane = tid & 63;
            const int m = lane & 15;
            const int quad = lane >> 4;

            int arow_node = node0 + wave * 16 + m;
            if (arow_node >= N_NODES) arow_node = N_NODES - 1;
            const unsigned short* ap = xbb + (size_t)arow_node * CH + quad * 8;

            bf16x8 afrag[4];
            #pragma unroll
            for (int kk = 0; kk < 4; ++kk)
                afrag[kk] = *(const bf16x8*)(ap + kk * 32);

            float gb[8];
            #pragma unroll
            for (int t = 0; t < 8; ++t)
                gb[t] = gate_b[t * 16 + m];

            #pragma unroll
            for (int t = 0; t < 8; ++t) {
                f32x4 c = {0.f, 0.f, 0.f, 0.f};
                const unsigned short* bp = gwb + (size_t)(t * 16 + m) * CH + quad * 8;
                #pragma unroll
                for (int kk = 0; kk < 4; ++kk) {
                    bf16x8 bfrag = *(const bf16x8*)(bp + kk * 32);
                    c = __builtin_amdgcn_mfma_f32_16x16x32_bf16(afrag[kk], bfrag, c, 0, 0, 0);
                }
                #pragma unroll
                for (int reg = 0; reg < 4; ++reg) {
                    const int r = wave * 16 + quad * 4 + reg;
                    const int col = t * 16 + m;
                    const float sp = spiral[r * PAD_ROW + col];
                    spiral[r * PAD_ROW + col] = sp * (c[reg] + gb[t]);
                }
            }
        }
        __syncthreads();

        // -- Phase 3: coalesced FP32 store --
        {
            #pragma unroll
            for (int p = 0; p < 8; ++p) {
                const int seg = p * 256 + tid;
                const int row = seg >> 5;
                const int c4 = (seg & 31) * 4;
                const int node = node0 + row;
                if (node < N_NODES) {
                    float4 v = *(const float4*)(spiral + row * PAD_ROW + c4);
                    *(float4*)(out + ((size_t)b * N_NODES + node) * CH + c4) = v;
                }
            }
        }
        __syncthreads();   // protect spiral/idx_s reuse by next unit
    }
}

// ---------------- Fallback: proven fp32 single kernel (used only if ws too small) ----------------
__global__ __launch_bounds__(256) void gated_spiral_kernel(
    const float* __restrict__ x,
    const int* __restrict__ indices,
    const float* __restrict__ weight,
    const float* __restrict__ gate_w,
    const float* __restrict__ gate_b,
    float* __restrict__ out)
{
    __shared__ float spiral[TILE * PAD_ROW];

    const int tile = blockIdx.x;
    const int b = blockIdx.y;
    const int tid = threadIdx.x;
    const int node0 = tile * TILE;

    const float* xb = x + (size_t)b * N_NODES * CH;

    {
        const int v = node0 + (tid >> 2);
        const int vc = v < N_NODES ? v : N_NODES - 1;
        const int q = tid & 3;

        int   idxv[SEQ];
        float wf[SEQ];
        const int*   ip = indices + (size_t)vc * SEQ;
        const float* wp = weight  + (size_t)vc * SEQ;
        #pragma unroll
        for (int s = 0; s < SEQ; ++s) {
            int t = ip[s];
            t = t < 0 ? 0 : t;
            idxv[s] = t >= N_NODES ? N_NODES - 1 : t;
            wf[s] = wp[s];
        }

        float acc[32];
        #pragma unroll
        for (int i = 0; i < 32; ++i) acc[i] = 0.f;

        #pragma unroll
        for (int s = 0; s < SEQ; ++s) {
            const float* row = xb + (size_t)idxv[s] * CH + q * 4;
            const float ws = wf[s];
            #pragma unroll
            for (int j = 0; j < 8; ++j) {
                float4 d = *(const float4*)(row + j * 16);
                acc[j*4+0] += ws * d.x;
                acc[j*4+1] += ws * d.y;
                acc[j*4+2] += ws * d.z;
                acc[j*4+3] += ws * d.w;
            }
        }

        const int vl = tid >> 2;
        #pragma unroll
        for (int j = 0; j < 8; ++j)
            *(float4*)(spiral + vl * PAD_ROW + j * 16 + q * 4) =
                make_float4(acc[j*4+0], acc[j*4+1], acc[j*4+2], acc[j*4+3]);
    }
    __syncthreads();

    {
        const int wave = tid >> 6;
        const int lane = tid & 63;
        const int m = lane & 15;
        const int quad = lane >> 4;

        int arow_node = node0 + wave * 16 + m;
        if (arow_node >= N_NODES) arow_node = N_NODES - 1;
        const float* ap = xb + (size_t)arow_node * CH + quad * 8;

        bf16x8 afrag[4];
        #pragma unroll
        for (int kk = 0; kk < 4; ++kk) {
            float4 lo = *(const float4*)(ap + kk * 32);
            float4 hi = *(const float4*)(ap + kk * 32 + 4);
            union { bf16x8 v; __hip_bfloat16 h[8]; } af;
            af.h[0] = __float2bfloat16(lo.x); af.h[1] = __float2bfloat16(lo.y);
            af.h[2] = __float2bfloat16(lo.z); af.h[3] = __float2bfloat16(lo.w);
            af.h[4] = __float2bfloat16(hi.x); af.h[5] = __float2bfloat16(hi.y);
            af.h[6] = __float2bfloat16(hi.z); af.h[7] = __float2bfloat16(hi.w);
            afrag[kk] = af.v;
        }

        float gb[8];
        #pragma unroll
        for (int t = 0; t < 8; ++t)
            gb[t] = gate_b[t * 16 + m];

        #pragma unroll
        for (int t = 0; t < 8; ++t) {
            f32x4 c = {0.f, 0.f, 0.f, 0.f};
            const float* bp = gate_w + (size_t)(t * 16 + m) * CH + quad * 8;
            #pragma unroll
            for (int kk = 0; kk < 4; ++kk) {
                float4 lo = *(const float4*)(bp + kk * 32);
                float4 hi = *(const float4*)(bp + kk * 32 + 4);
                union { bf16x8 v; __hip_bfloat16 h[8]; } bf;
                bf.h[0] = __float2bfloat16(lo.x); bf.h[1] = __float2bfloat16(lo.y);
                bf.h[2] = __float2bfloat16(lo.z); bf.h[3] = __float2bfloat16(lo.w);
                bf.h[4] = __float2bfloat16(hi.x); bf.h[5] = __float2bfloat16(hi.y);
                bf.h[6] = __float2bfloat16(hi.z); bf.h[7] = __float2bfloat16(hi.w);
                c = __builtin_amdgcn_mfma_f32_16x16x32_bf16(afrag[kk], bf.v, c, 0, 0, 0);
            }
            #pragma unroll
            for (int reg = 0; reg < 4; ++reg) {
                const int r = wave * 16 + quad * 4 + reg;
                const int col = t * 16 + m;
                const float sp = spiral[r * PAD_ROW + col];
                spiral[r * PAD_ROW + col] = sp * (c[reg] + gb[t]);
            }
        }
    }
    __syncthreads();

    {
        #pragma unroll
        for (int p = 0; p < 8; ++p) {
            const int seg = p * 256 + tid;
            const int row = seg >> 5;
            const int c4 = (seg & 31) * 4;
            const int node = node0 + row;
            if (node < N_NODES) {
                float4 v = *(const float4*)(spiral + row * PAD_ROW + c4);
                *(float4*)(out + ((size_t)b * N_NODES + node) * CH + c4) = v;
            }
        }
    }
}

extern "C" void kernel_launch(void* const* d_in, const int* in_sizes, int n_in,
                              void* d_out, int out_size, void* d_ws, size_t ws_size,
                              hipStream_t stream) {
    const float* x       = (const float*)d_in[0];
    const int*   indices = (const int*)d_in[1];
    const float* weight  = (const float*)d_in[2];
    const float* gate_w  = (const float*)d_in[3];
    const float* gate_b  = (const float*)d_in[4];
    float*       out     = (float*)d_out;

    const size_t x_bf_bytes  = (size_t)BS * N_NODES * CH * 2;   // 51,200,000
    const size_t gw_bf_bytes = (size_t)CH * CH * 2;             // 32,768

    if (ws_size >= x_bf_bytes + gw_bf_bytes) {
        unsigned short* xbuf = (unsigned short*)d_ws;
        unsigned short* gwb  = (unsigned short*)((char*)d_ws + x_bf_bytes);

        // Grid sized to guaranteed co-residency (occupancy API never over-estimates).
        static int s_nblk = 0;
        if (s_nblk == 0) {
            int per_cu = 0;
            hipError_t e = hipOccupancyMaxActiveBlocksPerMultiprocessor(
                &per_cu, fused_gated_spiral, 256, 0);
            if (e != hipSuccess || per_cu < 1) per_cu = 1;
            if (per_cu > 4) per_cu = 4;   // design target: 4 blocks/CU
            s_nblk = per_cu * 256;        // 256 CUs on MI355X
        }
        fused_gated_spiral<<<dim3(s_nblk), dim3(256), 0, stream>>>(
            x, indices, weight, gate_w, gate_b, xbuf, gwb, out, s_nblk);
    } else {
        dim3 grid((N_NODES + TILE - 1) / TILE, BS);
        gated_spiral_kernel<<<grid, dim3(256), 0, stream>>>(
            x, indices, weight, gate_w, gate_b, out);
    }
}

// Round 3
// 400.416 us; speedup vs baseline: 1.4619x; 1.4619x over previous
//
#include <hip/hip_runtime.h>
#include <hip/hip_bf16.h>

#define N_NODES 50000
#define SEQ 12
#define CH 128
#define BS 4
#define TILE 64
#define PAD_ROW 132            // floats per spiral LDS row (breaks 128-float bank stride)
#define NTILES ((N_NODES + TILE - 1) / TILE)   // 782

#define NODES_PER_WAVE 16
#define CHUNK_NODES 2
#define CHUNK_FLOATS (CHUNK_NODES * SEQ * CH)  // 3072 floats = 12 KB
#define NCHUNK (NODES_PER_WAVE / CHUNK_NODES)  // 8

typedef short bf16x8 __attribute__((ext_vector_type(8)));
typedef float f32x4 __attribute__((ext_vector_type(4)));

// Async global->LDS, 16B per lane. Global src is PER-LANE, LDS dst is wave-uniform
// base + lane*16 (m173 semantics) -> one instr gathers two 512B node rows.
__device__ __forceinline__ void gload_lds16(const float* g, float* l) {
    __builtin_amdgcn_global_load_lds(
        (const __attribute__((address_space(1))) void*)g,
        (__attribute__((address_space(3))) void*)l,
        16, 0, 0);
}

__global__ __launch_bounds__(256, 1) void gated_spiral_async(
    const float* __restrict__ x,
    const int* __restrict__ indices,
    const float* __restrict__ weight,
    const float* __restrict__ gate_w,
    const float* __restrict__ gate_b,
    float* __restrict__ out)
{
    __shared__ float spiral[TILE * PAD_ROW];        // 33792 B
    __shared__ float gbuf[4][2][CHUNK_FLOATS];      // 98304 B (per-wave double buffer)
    __shared__ int   idx_s[TILE * SEQ];             // 3072 B
    __shared__ float w_s[TILE * SEQ];               // 3072 B   -> total 138240 B, 1 block/CU

    const int tid  = threadIdx.x;
    const int wave = tid >> 6;
    const int lane = tid & 63;
    const int b    = blockIdx.y;
    const int node0 = blockIdx.x * TILE;
    const float* xb = x + (size_t)b * N_NODES * CH;

    // ---- Phase 0 (wave-local): stage this wave's 16 nodes' indices + weights ----
    const int sbase = wave * NODES_PER_WAVE * SEQ;  // 192 entries per wave
    #pragma unroll
    for (int k3 = 0; k3 < 3; ++k3) {
        const int k = k3 * 64 + lane;
        int node = node0 + wave * NODES_PER_WAVE + k / SEQ;
        if (node >= N_NODES) node = N_NODES - 1;
        int t = indices[(size_t)node * SEQ + (k % SEQ)];
        t = t < 0 ? 0 : (t >= N_NODES ? N_NODES - 1 : t);
        idx_s[sbase + k] = t;
        w_s[sbase + k]   = weight[(size_t)node * SEQ + (k % SEQ)];
    }
    // no barrier needed: same-wave LDS producer/consumer, compiler orders via lgkmcnt

    // ---- Phase 1: per-wave double-buffered async gather + weighted reduce ----
    {
        const int n  = lane >> 5;          // which of the 2 nodes in a chunk
        const int co = (lane & 31) * 4;    // float offset within a 512B row
        const int* idxw = idx_s + sbase;
        const float* ww = w_s + sbase;
        float* gb0 = &gbuf[wave][0][0];

        // prologue: issue chunks 0 and 1 (12 x 1KB each)
        #pragma unroll
        for (int c0 = 0; c0 < 2; ++c0) {
            const int* ix = idxw + c0 * CHUNK_NODES * SEQ;
            float* dst = gb0 + c0 * CHUNK_FLOATS;
            #pragma unroll
            for (int s = 0; s < SEQ; ++s) {
                const int row = ix[n * SEQ + s];
                gload_lds16(xb + (size_t)row * CH + co, dst + s * (CHUNK_NODES * CH));
            }
        }

        #pragma unroll
        for (int c = 0; c < NCHUNK; ++c) {
            // counted wait: <=12 outstanding => current chunk fully landed
            // (vmcnt retires in order; any older staging loads retired first)
            if (c < NCHUNK - 1) asm volatile("s_waitcnt vmcnt(12)" ::: "memory");
            else                asm volatile("s_waitcnt vmcnt(0)"  ::: "memory");
            __builtin_amdgcn_sched_barrier(0);

            float* cur = gb0 + (c & 1) * CHUNK_FLOATS;
            const float* wp = ww + c * CHUNK_NODES * SEQ + n * SEQ;
            float a0 = 0.f, a1 = 0.f, a2 = 0.f, a3 = 0.f;
            #pragma unroll
            for (int s = 0; s < SEQ; ++s) {
                const float4 d = *(const float4*)(cur + (s * CHUNK_NODES + n) * CH + co);
                const float ws = wp[s];
                a0 += ws * d.x; a1 += ws * d.y; a2 += ws * d.z; a3 += ws * d.w;
            }
            const int r = wave * NODES_PER_WAVE + c * CHUNK_NODES + n;
            *(float4*)(spiral + r * PAD_ROW + co) = make_float4(a0, a1, a2, a3);

            if (c + 2 < NCHUNK) {
                // drain ds_reads of this buffer before async loads overwrite it
                asm volatile("s_waitcnt lgkmcnt(0)" ::: "memory");
                __builtin_amdgcn_sched_barrier(0);
                const int* ix = idxw + (c + 2) * CHUNK_NODES * SEQ;
                #pragma unroll
                for (int s = 0; s < SEQ; ++s) {
                    const int row = ix[n * SEQ + s];
                    gload_lds16(xb + (size_t)row * CH + co, cur + s * (CHUNK_NODES * CH));
                }
            }
        }
    }
    // no __syncthreads: phases 2 and 3 only touch this wave's own 16 spiral rows

    // ---- Phase 2: gate GEMM via MFMA 16x16x32_bf16 (proven layout), wave-local ----
    {
        const int m = lane & 15;
        const int quad = lane >> 4;

        int arow_node = node0 + wave * 16 + m;
        if (arow_node >= N_NODES) arow_node = N_NODES - 1;
        const float* ap = xb + (size_t)arow_node * CH + quad * 8;

        bf16x8 afrag[4];
        #pragma unroll
        for (int kk = 0; kk < 4; ++kk) {
            float4 lo = *(const float4*)(ap + kk * 32);
            float4 hi = *(const float4*)(ap + kk * 32 + 4);
            union { bf16x8 v; __hip_bfloat16 h[8]; } af;
            af.h[0] = __float2bfloat16(lo.x); af.h[1] = __float2bfloat16(lo.y);
            af.h[2] = __float2bfloat16(lo.z); af.h[3] = __float2bfloat16(lo.w);
            af.h[4] = __float2bfloat16(hi.x); af.h[5] = __float2bfloat16(hi.y);
            af.h[6] = __float2bfloat16(hi.z); af.h[7] = __float2bfloat16(hi.w);
            afrag[kk] = af.v;
        }

        float gbv[8];
        #pragma unroll
        for (int t = 0; t < 8; ++t)
            gbv[t] = gate_b[t * 16 + m];

        #pragma unroll
        for (int t = 0; t < 8; ++t) {
            f32x4 c = {0.f, 0.f, 0.f, 0.f};
            const float* bp = gate_w + (size_t)(t * 16 + m) * CH + quad * 8;
            #pragma unroll
            for (int kk = 0; kk < 4; ++kk) {
                float4 lo = *(const float4*)(bp + kk * 32);
                float4 hi = *(const float4*)(bp + kk * 32 + 4);
                union { bf16x8 v; __hip_bfloat16 h[8]; } bf;
                bf.h[0] = __float2bfloat16(lo.x); bf.h[1] = __float2bfloat16(lo.y);
                bf.h[2] = __float2bfloat16(lo.z); bf.h[3] = __float2bfloat16(lo.w);
                bf.h[4] = __float2bfloat16(hi.x); bf.h[5] = __float2bfloat16(hi.y);
                bf.h[6] = __float2bfloat16(hi.z); bf.h[7] = __float2bfloat16(hi.w);
                c = __builtin_amdgcn_mfma_f32_16x16x32_bf16(afrag[kk], bf.v, c, 0, 0, 0);
            }
            #pragma unroll
            for (int reg = 0; reg < 4; ++reg) {
                const int r = wave * 16 + quad * 4 + reg;
                const int col = t * 16 + m;
                const float sp = spiral[r * PAD_ROW + col];
                spiral[r * PAD_ROW + col] = sp * (c[reg] + gbv[t]);
            }
        }
    }

    // ---- Phase 3: wave-local coalesced store (nontemporal: don't pollute L2) ----
    {
        #pragma unroll
        for (int p = 0; p < 8; ++p) {
            const int seg = p * 64 + lane;          // 512 float4-segments per wave
            const int r = seg >> 5;                 // 0..15
            const int c4 = (seg & 31) * 4;
            const int node = node0 + wave * 16 + r;
            if (node < N_NODES) {
                const float* sp = spiral + (wave * 16 + r) * PAD_ROW + c4;
                f32x4 v = { sp[0], sp[1], sp[2], sp[3] };
                __builtin_nontemporal_store(v, (f32x4*)(out + ((size_t)b * N_NODES + node) * CH + c4));
            }
        }
    }
}

extern "C" void kernel_launch(void* const* d_in, const int* in_sizes, int n_in,
                              void* d_out, int out_size, void* d_ws, size_t ws_size,
                              hipStream_t stream) {
    const float* x       = (const float*)d_in[0];
    const int*   indices = (const int*)d_in[1];
    const float* weight  = (const float*)d_in[2];
    const float* gate_w  = (const float*)d_in[3];
    const float* gate_b  = (const float*)d_in[4];
    float*       out     = (float*)d_out;

    dim3 grid(NTILES, BS);   // x-fastest dispatch -> one batch's tiles run together (L2 locality)
    gated_spiral_async<<<grid, dim3(256), 0, stream>>>(
        x, indices, weight, gate_w, gate_b, out);
}

// Round 4
// 324.164 us; speedup vs baseline: 1.8057x; 1.2352x over previous
//
#include <hip/hip_runtime.h>
#include <hip/hip_bf16.h>

#define N_NODES 50000
#define SEQ 12
#define CH 128
#define BS 4
#define TILE 64
#define NTILES ((N_NODES + TILE - 1) / TILE)   // 782
#define HALF 64            // output channels per slice-block
#define PAD_S 68           // spiral row stride (floats) for 64-ch slice
#define PAD_ROW 132        // fallback kernel row stride

// slice-gather geometry: per wave 16 nodes, chunks of 4 nodes
#define CNODES 4
#define NCHUNK 4
#define CHUNK_SHORTS (CNODES * SEQ * HALF)   // 3072 bf16 = 6 KB = 6 x 1KB instrs
#define CHUNK_INSTR (CHUNK_SHORTS / 512)     // 6

typedef short bf16x8 __attribute__((ext_vector_type(8)));
typedef float f32x4 __attribute__((ext_vector_type(4)));

__device__ __forceinline__ float bflo(unsigned int u) { return __uint_as_float(u << 16); }
__device__ __forceinline__ float bfhi(unsigned int u) { return __uint_as_float(u & 0xFFFF0000u); }

// Async global->LDS, 16B/lane. Global src per-lane, LDS dst = uniform base + lane*16.
__device__ __forceinline__ void gload_lds16b(const unsigned short* g, unsigned short* l) {
    __builtin_amdgcn_global_load_lds(
        (const __attribute__((address_space(1))) void*)g,
        (__attribute__((address_space(3))) void*)l,
        16, 0, 0);
}
__device__ __forceinline__ void gload_lds16f(const float* g, float* l) {
    __builtin_amdgcn_global_load_lds(
        (const __attribute__((address_space(1))) void*)g,
        (__attribute__((address_space(3))) void*)l,
        16, 0, 0);
}

// ---------------- Kernel A: fp32 -> bf16 conversion of x ----------------
__global__ __launch_bounds__(256) void convert_kernel(
    const float* __restrict__ x,
    unsigned short* __restrict__ xb)
{
    const size_t i = (size_t)blockIdx.x * 256 + threadIdx.x;   // one thread per 8 elems
    const size_t n8 = (size_t)BS * N_NODES * CH / 8;           // 3,200,000
    if (i < n8) {
        float4 lo = *(const float4*)(x + i * 8);
        float4 hi = *(const float4*)(x + i * 8 + 4);
        union { bf16x8 v; __hip_bfloat16 h[8]; } o;
        o.h[0] = __float2bfloat16(lo.x); o.h[1] = __float2bfloat16(lo.y);
        o.h[2] = __float2bfloat16(lo.z); o.h[3] = __float2bfloat16(lo.w);
        o.h[4] = __float2bfloat16(hi.x); o.h[5] = __float2bfloat16(hi.y);
        o.h[6] = __float2bfloat16(hi.z); o.h[7] = __float2bfloat16(hi.w);
        *(bf16x8*)(xb + i * 8) = o.v;
    }
}

// ---------------- Kernel B: L2-resident sliced gather + MFMA gate ----------------
// block = (tile, group); group = (batch, half) pinned to one XCD via blockIdx & 7.
__global__ __launch_bounds__(256, 2) void gated_spiral_slice(
    const unsigned short* __restrict__ xb,
    const int* __restrict__ indices,
    const float* __restrict__ weight,
    const float* __restrict__ gate_w,
    const float* __restrict__ gate_b,
    float* __restrict__ out)
{
    __shared__ float spiral[TILE * PAD_S];                 // 17408 B
    __shared__ unsigned short gbuf[4][2][CHUNK_SHORTS];    // 49152 B
    __shared__ int   idx_s[TILE * SEQ];                    // 3072 B
    __shared__ float w_s[TILE * SEQ];                      // 3072 B -> 72704 B, 2 blk/CU

    const int tid  = threadIdx.x;
    const int wave = tid >> 6;
    const int lane = tid & 63;

    const int grp  = blockIdx.x & 7;       // (batch, half) -> one XCD (round-robin heuristic)
    const int b    = grp >> 1;
    const int half = grp & 1;
    const int tile = blockIdx.x >> 3;
    const int node0 = tile * TILE;
    const unsigned short* xbb = xb + (size_t)b * N_NODES * CH;

    // ---- Phase 0 (wave-local): stage this wave's 16 nodes' indices + weights ----
    const int sbase = wave * 16 * SEQ;     // 192 entries/wave
    #pragma unroll
    for (int k3 = 0; k3 < 3; ++k3) {
        const int k = k3 * 64 + lane;
        int node = node0 + wave * 16 + k / SEQ;
        if (node >= N_NODES) node = N_NODES - 1;
        int t = indices[(size_t)node * SEQ + (k % SEQ)];
        t = t < 0 ? 0 : (t >= N_NODES ? N_NODES - 1 : t);
        idx_s[sbase + k] = t;
        w_s[sbase + k]   = weight[(size_t)node * SEQ + (k % SEQ)];
    }
    // same-wave LDS producer/consumer: ordered via lgkmcnt by the compiler

    // ---- Phase 1: per-wave double-buffered async slice gather + weighted reduce ----
    {
        const int* idxw = idx_s + sbase;
        const float* ww = w_s + sbase;
        unsigned short* gw0 = &gbuf[wave][0][0];
        const int lrs = lane >> 3;          // sub-row within a 1KB instr (8 rows/instr)
        const int lco = (lane & 7) * 8;     // bf16 elems within a 128B row slice

        // prologue: issue chunks 0 and 1
        #pragma unroll
        for (int c0 = 0; c0 < 2; ++c0) {
            unsigned short* dst = gw0 + c0 * CHUNK_SHORTS;
            #pragma unroll
            for (int i = 0; i < CHUNK_INSTR; ++i) {
                const int rs = i * 8 + lrs;        // 0..47 = s*4 + n
                const int s = rs >> 2, n = rs & 3;
                const int row = idxw[(c0 * CNODES + n) * SEQ + s];
                gload_lds16b(xbb + (size_t)row * CH + half * HALF + lco, dst + i * 512);
            }
        }

        #pragma unroll
        for (int c = 0; c < NCHUNK; ++c) {
            if (c < NCHUNK - 1) asm volatile("s_waitcnt vmcnt(6)" ::: "memory");
            else                asm volatile("s_waitcnt vmcnt(0)" ::: "memory");
            __builtin_amdgcn_sched_barrier(0);

            unsigned short* bufp = gw0 + (c & 1) * CHUNK_SHORTS;
            const int nr = lane >> 4;            // node within chunk (0..3)
            const int cc = (lane & 15) * 4;      // channel (in slice) this lane owns
            const float* wp = ww + (c * CNODES + nr) * SEQ;
            float a0 = 0.f, a1 = 0.f, a2 = 0.f, a3 = 0.f;
            #pragma unroll
            for (int s = 0; s < SEQ; ++s) {
                const uint2 d = *(const uint2*)(bufp + (s * 4 + nr) * HALF + cc);
                const float ws = wp[s];
                a0 += ws * bflo(d.x); a1 += ws * bfhi(d.x);
                a2 += ws * bflo(d.y); a3 += ws * bfhi(d.y);
            }
            const int r = wave * 16 + c * CNODES + nr;
            *(float4*)(spiral + r * PAD_S + cc) = make_float4(a0, a1, a2, a3);

            if (c + 2 < NCHUNK) {
                // drain ds_reads of this buffer before async loads overwrite it
                asm volatile("s_waitcnt lgkmcnt(0)" ::: "memory");
                __builtin_amdgcn_sched_barrier(0);
                #pragma unroll
                for (int i = 0; i < CHUNK_INSTR; ++i) {
                    const int rs = i * 8 + lrs;
                    const int s = rs >> 2, n = rs & 3;
                    const int row = idxw[((c + 2) * CNODES + n) * SEQ + s];
                    gload_lds16b(xbb + (size_t)row * CH + half * HALF + lco, bufp + i * 512);
                }
            }
        }
    }
    // no __syncthreads anywhere: all phases wave-local

    // ---- Phase 2: gate GEMM (sliced D: 16 nodes x 64 out-ch per wave) ----
    {
        const int m = lane & 15;
        const int quad = lane >> 4;

        int arow_node = node0 + wave * 16 + m;
        if (arow_node >= N_NODES) arow_node = N_NODES - 1;
        const unsigned short* ap = xbb + (size_t)arow_node * CH + quad * 8;

        bf16x8 afrag[4];
        #pragma unroll
        for (int kk = 0; kk < 4; ++kk)
            afrag[kk] = *(const bf16x8*)(ap + kk * 32);

        float gbv[4];
        #pragma unroll
        for (int t = 0; t < 4; ++t)
            gbv[t] = gate_b[half * HALF + t * 16 + m];

        #pragma unroll
        for (int t = 0; t < 4; ++t) {
            f32x4 c = {0.f, 0.f, 0.f, 0.f};
            const float* bp = gate_w + (size_t)(half * HALF + t * 16 + m) * CH + quad * 8;
            #pragma unroll
            for (int kk = 0; kk < 4; ++kk) {
                float4 lo = *(const float4*)(bp + kk * 32);
                float4 hi = *(const float4*)(bp + kk * 32 + 4);
                union { bf16x8 v; __hip_bfloat16 h[8]; } bf;
                bf.h[0] = __float2bfloat16(lo.x); bf.h[1] = __float2bfloat16(lo.y);
                bf.h[2] = __float2bfloat16(lo.z); bf.h[3] = __float2bfloat16(lo.w);
                bf.h[4] = __float2bfloat16(hi.x); bf.h[5] = __float2bfloat16(hi.y);
                bf.h[6] = __float2bfloat16(hi.z); bf.h[7] = __float2bfloat16(hi.w);
                c = __builtin_amdgcn_mfma_f32_16x16x32_bf16(afrag[kk], bf.v, c, 0, 0, 0);
            }
            #pragma unroll
            for (int reg = 0; reg < 4; ++reg) {
                const int r = wave * 16 + quad * 4 + reg;
                const int col = t * 16 + m;                    // out-ch within slice
                const float sp = spiral[r * PAD_S + col];
                spiral[r * PAD_S + col] = sp * (c[reg] + gbv[t]);
            }
        }
    }

    // ---- Phase 3: wave-local coalesced slice store (nontemporal) ----
    {
        #pragma unroll
        for (int p = 0; p < 4; ++p) {
            const int seg = p * 64 + lane;        // 256 float4-segments per wave
            const int r = seg >> 4;               // 0..15
            const int cc = (seg & 15) * 4;        // 0..60
            const int node = node0 + wave * 16 + r;
            if (node < N_NODES) {
                const float* sp = spiral + (wave * 16 + r) * PAD_S + cc;
                f32x4 v = { sp[0], sp[1], sp[2], sp[3] };
                __builtin_nontemporal_store(v,
                    (f32x4*)(out + ((size_t)b * N_NODES + node) * CH + half * HALF + cc));
            }
        }
    }
}

// ---------------- Fallback: proven round-3 fp32 async kernel (ws too small) ----------------
#define NODES_PER_WAVE 16
#define FCHUNK_NODES 2
#define FCHUNK_FLOATS (FCHUNK_NODES * SEQ * CH)  // 3072 floats = 12 KB
#define FNCHUNK (NODES_PER_WAVE / FCHUNK_NODES)  // 8

__global__ __launch_bounds__(256, 1) void gated_spiral_async(
    const float* __restrict__ x,
    const int* __restrict__ indices,
    const float* __restrict__ weight,
    const float* __restrict__ gate_w,
    const float* __restrict__ gate_b,
    float* __restrict__ out)
{
    __shared__ float spiral[TILE * PAD_ROW];
    __shared__ float gbuf[4][2][FCHUNK_FLOATS];
    __shared__ int   idx_s[TILE * SEQ];
    __shared__ float w_s[TILE * SEQ];

    const int tid  = threadIdx.x;
    const int wave = tid >> 6;
    const int lane = tid & 63;
    const int b    = blockIdx.y;
    const int node0 = blockIdx.x * TILE;
    const float* xb = x + (size_t)b * N_NODES * CH;

    const int sbase = wave * NODES_PER_WAVE * SEQ;
    #pragma unroll
    for (int k3 = 0; k3 < 3; ++k3) {
        const int k = k3 * 64 + lane;
        int node = node0 + wave * NODES_PER_WAVE + k / SEQ;
        if (node >= N_NODES) node = N_NODES - 1;
        int t = indices[(size_t)node * SEQ + (k % SEQ)];
        t = t < 0 ? 0 : (t >= N_NODES ? N_NODES - 1 : t);
        idx_s[sbase + k] = t;
        w_s[sbase + k]   = weight[(size_t)node * SEQ + (k % SEQ)];
    }

    {
        const int n  = lane >> 5;
        const int co = (lane & 31) * 4;
        const int* idxw = idx_s + sbase;
        const float* ww = w_s + sbase;
        float* gb0 = &gbuf[wave][0][0];

        #pragma unroll
        for (int c0 = 0; c0 < 2; ++c0) {
            const int* ix = idxw + c0 * FCHUNK_NODES * SEQ;
            float* dst = gb0 + c0 * FCHUNK_FLOATS;
            #pragma unroll
            for (int s = 0; s < SEQ; ++s) {
                const int row = ix[n * SEQ + s];
                gload_lds16f(xb + (size_t)row * CH + co, dst + s * (FCHUNK_NODES * CH));
            }
        }

        #pragma unroll
        for (int c = 0; c < FNCHUNK; ++c) {
            if (c < FNCHUNK - 1) asm volatile("s_waitcnt vmcnt(12)" ::: "memory");
            else                 asm volatile("s_waitcnt vmcnt(0)"  ::: "memory");
            __builtin_amdgcn_sched_barrier(0);

            float* cur = gb0 + (c & 1) * FCHUNK_FLOATS;
            const float* wp = ww + c * FCHUNK_NODES * SEQ + n * SEQ;
            float a0 = 0.f, a1 = 0.f, a2 = 0.f, a3 = 0.f;
            #pragma unroll
            for (int s = 0; s < SEQ; ++s) {
                const float4 d = *(const float4*)(cur + (s * FCHUNK_NODES + n) * CH + co);
                const float ws = wp[s];
                a0 += ws * d.x; a1 += ws * d.y; a2 += ws * d.z; a3 += ws * d.w;
            }
            const int r = wave * NODES_PER_WAVE + c * FCHUNK_NODES + n;
            *(float4*)(spiral + r * PAD_ROW + co) = make_float4(a0, a1, a2, a3);

            if (c + 2 < FNCHUNK) {
                asm volatile("s_waitcnt lgkmcnt(0)" ::: "memory");
                __builtin_amdgcn_sched_barrier(0);
                const int* ix = idxw + (c + 2) * FCHUNK_NODES * SEQ;
                #pragma unroll
                for (int s = 0; s < SEQ; ++s) {
                    const int row = ix[n * SEQ + s];
                    gload_lds16f(xb + (size_t)row * CH + co, cur + s * (FCHUNK_NODES * CH));
                }
            }
        }
    }

    {
        const int m = lane & 15;
        const int quad = lane >> 4;

        int arow_node = node0 + wave * 16 + m;
        if (arow_node >= N_NODES) arow_node = N_NODES - 1;
        const float* ap = xb + (size_t)arow_node * CH + quad * 8;

        bf16x8 afrag[4];
        #pragma unroll
        for (int kk = 0; kk < 4; ++kk) {
            float4 lo = *(const float4*)(ap + kk * 32);
            float4 hi = *(const float4*)(ap + kk * 32 + 4);
            union { bf16x8 v; __hip_bfloat16 h[8]; } af;
            af.h[0] = __float2bfloat16(lo.x); af.h[1] = __float2bfloat16(lo.y);
            af.h[2] = __float2bfloat16(lo.z); af.h[3] = __float2bfloat16(lo.w);
            af.h[4] = __float2bfloat16(hi.x); af.h[5] = __float2bfloat16(hi.y);
            af.h[6] = __float2bfloat16(hi.z); af.h[7] = __float2bfloat16(hi.w);
            afrag[kk] = af.v;
        }

        float gbv[8];
        #pragma unroll
        for (int t = 0; t < 8; ++t)
            gbv[t] = gate_b[t * 16 + m];

        #pragma unroll
        for (int t = 0; t < 8; ++t) {
            f32x4 c = {0.f, 0.f, 0.f, 0.f};
            const float* bp = gate_w + (size_t)(t * 16 + m) * CH + quad * 8;
            #pragma unroll
            for (int kk = 0; kk < 4; ++kk) {
                float4 lo = *(const float4*)(bp + kk * 32);
                float4 hi = *(const float4*)(bp + kk * 32 + 4);
                union { bf16x8 v; __hip_bfloat16 h[8]; } bf;
                bf.h[0] = __float2bfloat16(lo.x); bf.h[1] = __float2bfloat16(lo.y);
                bf.h[2] = __float2bfloat16(lo.z); bf.h[3] = __float2bfloat16(lo.w);
                bf.h[4] = __float2bfloat16(hi.x); bf.h[5] = __float2bfloat16(hi.y);
                bf.h[6] = __float2bfloat16(hi.z); bf.h[7] = __float2bfloat16(hi.w);
                c = __builtin_amdgcn_mfma_f32_16x16x32_bf16(afrag[kk], bf.v, c, 0, 0, 0);
            }
            #pragma unroll
            for (int reg = 0; reg < 4; ++reg) {
                const int r = wave * 16 + quad * 4 + reg;
                const int col = t * 16 + m;
                const float sp = spiral[r * PAD_ROW + col];
                spiral[r * PAD_ROW + col] = sp * (c[reg] + gbv[t]);
            }
        }
    }

    {
        #pragma unroll
        for (int p = 0; p < 8; ++p) {
            const int seg = p * 64 + lane;
            const int r = seg >> 5;
            const int c4 = (seg & 31) * 4;
            const int node = node0 + wave * 16 + r;
            if (node < N_NODES) {
                const float* sp = spiral + (wave * 16 + r) * PAD_ROW + c4;
                f32x4 v = { sp[0], sp[1], sp[2], sp[3] };
                __builtin_nontemporal_store(v, (f32x4*)(out + ((size_t)b * N_NODES + node) * CH + c4));
            }
        }
    }
}

extern "C" void kernel_launch(void* const* d_in, const int* in_sizes, int n_in,
                              void* d_out, int out_size, void* d_ws, size_t ws_size,
                              hipStream_t stream) {
    const float* x       = (const float*)d_in[0];
    const int*   indices = (const int*)d_in[1];
    const float* weight  = (const float*)d_in[2];
    const float* gate_w  = (const float*)d_in[3];
    const float* gate_b  = (const float*)d_in[4];
    float*       out     = (float*)d_out;

    const size_t x_bf_bytes = (size_t)BS * N_NODES * CH * 2;   // 51,200,000

    if (ws_size >= x_bf_bytes) {
        unsigned short* xbuf = (unsigned short*)d_ws;
        const size_t n8 = (size_t)BS * N_NODES * CH / 8;       // 3,200,000
        convert_kernel<<<dim3((unsigned)((n8 + 255) / 256)), dim3(256), 0, stream>>>(x, xbuf);
        gated_spiral_slice<<<dim3(NTILES * 8), dim3(256), 0, stream>>>(
            xbuf, indices, weight, gate_w, gate_b, out);
    } else {
        dim3 grid(NTILES, BS);
        gated_spiral_async<<<grid, dim3(256), 0, stream>>>(
            x, indices, weight, gate_w, gate_b, out);
    }
}